// Round 9
// baseline (180.363 us; speedup 1.0000x reference)
//
#include <hip/hip_runtime.h>

// UniformBottomUpHTMM: T=64 trees, depth 10 (N1=2047 heap), C=16, M=64,
// G=16. r20: column-major matvec + node-pair batching. r19 (fences,
// VGPR=108, zero spill) = 56us at VALUBusy 27.6% -- occupancy is now
// GRID-capped (1024 blocks = 4/CU x 4 waves = 16 waves/CU max), so the
// remaining 72% stall must fall to per-wave ILP / less work per node.
// Old matvec: 64 uniform ds_read_b128 (A rows) + 16 serial hsum4 chains.
// Changes:
//  1. A stored TRANSPOSED in LDS (sAt[j][i], free in setup). Matvec goes
//     column-major: T[q] += s_j * Acol_j[q] -- zero hsums (was 48 adds),
//     4 independent accumulator chains, one final hsum for nu.
//  2. Node-pair batching: the two L9 matvecs per thread are independent;
//     ONE shared A-column load stream feeds both (A-reads halved, FMA per
//     load doubled). Same in L7 + tail (2 nodes/thread), where child
//     reads become single conflict-free b128 (4 contiguous floats).
//  3. sched_barrier(0) every 2 j inside the matvec loops: caps in-flight
//     column loads (~32 regs) -- the r17 register-ballooning hazard.
// Tripwire: VGPR>168 or WRITE_SIZE>>4KB => regression path, revert.
// Structure: 1024 independent blocks, one (t,g) each, no workspace/atomics.

#define C_DIM 16
#define M_DIM 64
#define G_DIM 16
#define T_TREES 64
#define N1 2047
#define NBLOCKS (T_TREES * G_DIM)   // 1024
#define BTS 20                      // padded row stride (floats) for xv-tables

__device__ __forceinline__ float4 f4add(float4 a, float4 b) {
    return make_float4(a.x + b.x, a.y + b.y, a.z + b.z, a.w + b.w);
}
__device__ __forceinline__ float4 f4mul(float4 a, float4 b) {
    return make_float4(a.x * b.x, a.y * b.y, a.z * b.z, a.w * b.w);
}
__device__ __forceinline__ float4 f4fmas(float4 a, float s, float4 c) {
    return make_float4(fmaf(a.x, s, c.x), fmaf(a.y, s, c.y),
                       fmaf(a.z, s, c.z), fmaf(a.w, s, c.w));
}
__device__ __forceinline__ float hsum4(float4 a) { return a.x + a.y + a.z + a.w; }
__device__ __forceinline__ float f4get(const float4 v, const int c) {
    return c == 0 ? v.x : c == 1 ? v.y : c == 2 ? v.z : v.w;
}

// Dual column-major matvec: two independent nodes share one A-column
// load stream. T[q].r = sum_j A[4q+r][j]*s[j]; bp[q]=T[q]*Bt4[q].
__device__ __forceinline__ void colmv2(const float* __restrict__ At,
    const float* __restrict__ bta, const float* __restrict__ btb,
    const float4 sa[4], const float4 sb[4],
    float4 bpa[4], float4 bpb[4], float& nua, float& nub)
{
    float4 Ta0 = make_float4(0.f,0.f,0.f,0.f), Ta1 = Ta0, Ta2 = Ta0, Ta3 = Ta0;
    float4 Tb0 = Ta0, Tb1 = Ta0, Tb2 = Ta0, Tb3 = Ta0;
    #pragma unroll
    for (int j = 0; j < 16; ++j) {
        const float4* cp = (const float4*)(At + j * 16);
        const float4 c0 = cp[0], c1 = cp[1], c2 = cp[2], c3 = cp[3];
        const float aj = f4get(sa[j >> 2], j & 3);
        const float bj = f4get(sb[j >> 2], j & 3);
        Ta0 = f4fmas(c0, aj, Ta0); Ta1 = f4fmas(c1, aj, Ta1);
        Ta2 = f4fmas(c2, aj, Ta2); Ta3 = f4fmas(c3, aj, Ta3);
        Tb0 = f4fmas(c0, bj, Tb0); Tb1 = f4fmas(c1, bj, Tb1);
        Tb2 = f4fmas(c2, bj, Tb2); Tb3 = f4fmas(c3, bj, Tb3);
        if ((j & 1) == 1) __builtin_amdgcn_sched_barrier(0);  // cap in-flight loads
    }
    bpa[0] = f4mul(Ta0, *(const float4*)(bta +  0));
    bpa[1] = f4mul(Ta1, *(const float4*)(bta +  4));
    bpa[2] = f4mul(Ta2, *(const float4*)(bta +  8));
    bpa[3] = f4mul(Ta3, *(const float4*)(bta + 12));
    bpb[0] = f4mul(Tb0, *(const float4*)(btb +  0));
    bpb[1] = f4mul(Tb1, *(const float4*)(btb +  4));
    bpb[2] = f4mul(Tb2, *(const float4*)(btb +  8));
    bpb[3] = f4mul(Tb3, *(const float4*)(btb + 12));
    nua = hsum4(f4add(f4add(bpa[0], bpa[1]), f4add(bpa[2], bpa[3])));
    nub = hsum4(f4add(f4add(bpb[0], bpb[1]), f4add(bpb[2], bpb[3])));
}

// Single column-major matvec.
__device__ __forceinline__ float colmv(const float* __restrict__ At,
    const float* __restrict__ bt, const float4 sv[4], float4 bp[4])
{
    float4 T0 = make_float4(0.f,0.f,0.f,0.f), T1 = T0, T2 = T0, T3 = T0;
    #pragma unroll
    for (int j = 0; j < 16; ++j) {
        const float4* cp = (const float4*)(At + j * 16);
        const float sj = f4get(sv[j >> 2], j & 3);
        T0 = f4fmas(cp[0], sj, T0); T1 = f4fmas(cp[1], sj, T1);
        T2 = f4fmas(cp[2], sj, T2); T3 = f4fmas(cp[3], sj, T3);
        if ((j & 1) == 1) __builtin_amdgcn_sched_barrier(0);
    }
    bp[0] = f4mul(T0, *(const float4*)(bt +  0));
    bp[1] = f4mul(T1, *(const float4*)(bt +  4));
    bp[2] = f4mul(T2, *(const float4*)(bt +  8));
    bp[3] = f4mul(T3, *(const float4*)(bt + 12));
    return hsum4(f4add(f4add(bp[0], bp[1]), f4add(bp[2], bp[3])));
}

__global__ __launch_bounds__(256, 1) void htmm_fused(
    const int* __restrict__ x,
    const int* __restrict__ inv_map,
    const float* __restrict__ lA,
    const float* __restrict__ lB,
    const float* __restrict__ lPi,
    float* __restrict__ out)
{
    const int bid = blockIdx.x;           // 1024 blocks: g = bid>>6, t = bid&63
    const int tid = threadIdx.x;
    const int g = bid >> 6;
    const int t = bid & (T_TREES - 1);

    __shared__ __align__(16) float sAt[C_DIM * C_DIM];   // TRANSPOSED A: sAt[j*16+i]=A[i][j]
    __shared__ __align__(16) float sBt[M_DIM * BTS];     // Bt[xv][c], stride 20
    __shared__ __align__(16) float sPB[M_DIM * BTS];     // 0.5*Pi*B/nu per xv
    __shared__ float sLog[M_DIM];                        // log(nu_leaf(xv))
    __shared__ float sPi[C_DIM];
    __shared__ __align__(16) unsigned char xs[2048];
    __shared__ float buf0[C_DIM * 256];   // L8 betas (SoA stride 256)
    __shared__ float buf1[C_DIM * 128];
    __shared__ float wsum[4];

    // ---- tree symbols (coalesced; 16 same-tree blocks share L2) ----
    {
        const int base = t * N1;
        for (int i = tid; i < N1; i += 256)
            xs[i] = (unsigned char)x[inv_map[base + i]];
    }
    // ---- A softmax (over i within 16-lane segments), stored TRANSPOSED ----
    {
        int j = tid >> 4, i = tid & 15;
        float v = lA[(i * C_DIM + j) * G_DIM + g];
        float mx = v;
        #pragma unroll
        for (int m = 1; m < 16; m <<= 1) mx = fmaxf(mx, __shfl_xor(mx, m, 16));
        float e = __expf(v - mx);
        float s = e;
        #pragma unroll
        for (int m = 1; m < 16; m <<= 1) s += __shfl_xor(s, m, 16);
        sAt[j * C_DIM + i] = e / s;   // addr == tid: conflict-free
    }
    // ---- B softmax (over m), written TRANSPOSED: sBt[xv*BTS + c] ----
    {
        int c = tid >> 4, l16 = tid & 15;
        float e0 = lB[(c * M_DIM + l16 +  0) * G_DIM + g];
        float e1 = lB[(c * M_DIM + l16 + 16) * G_DIM + g];
        float e2 = lB[(c * M_DIM + l16 + 32) * G_DIM + g];
        float e3 = lB[(c * M_DIM + l16 + 48) * G_DIM + g];
        float mx = fmaxf(fmaxf(e0, e1), fmaxf(e2, e3));
        #pragma unroll
        for (int m = 1; m < 16; m <<= 1) mx = fmaxf(mx, __shfl_xor(mx, m, 16));
        e0 = __expf(e0 - mx); e1 = __expf(e1 - mx);
        e2 = __expf(e2 - mx); e3 = __expf(e3 - mx);
        float s = e0 + e1 + e2 + e3;
        #pragma unroll
        for (int m = 1; m < 16; m <<= 1) s += __shfl_xor(s, m, 16);
        float inv = 1.f / s;
        sBt[(l16 +  0) * BTS + c] = e0 * inv;
        sBt[(l16 + 16) * BTS + c] = e1 * inv;
        sBt[(l16 + 32) * BTS + c] = e2 * inv;
        sBt[(l16 + 48) * BTS + c] = e3 * inv;
    }
    if (tid < C_DIM) {  // Pi softmax
        float v = lPi[tid * G_DIM + g];
        float mx = v;
        #pragma unroll
        for (int m = 1; m < 16; m <<= 1) mx = fmaxf(mx, __shfl_xor(mx, m, 16));
        float e = __expf(v - mx);
        float s = e;
        #pragma unroll
        for (int m = 1; m < 16; m <<= 1) s += __shfl_xor(s, m, 16);
        sPi[tid] = e / s;
    }
    __syncthreads();

    // ---- leaf tables: PB[xv][k] = 0.5*Pi[k]*Bt[xv][k]/nu, logNu[xv] ----
    if (tid < M_DIM) {
        const int xv = tid;
        float pb[16]; float nu = 0.f;
        #pragma unroll
        for (int k = 0; k < 16; ++k) {
            pb[k] = sPi[k] * sBt[xv * BTS + k];
            nu += pb[k];
        }
        const float inv = 0.5f / nu;
        #pragma unroll
        for (int k = 0; k < 16; ++k) sPB[xv * BTS + k] = pb[k] * inv;
        sLog[xv] = __logf(nu);
    }
    __syncthreads();

    float ll = 0.f;

    // ---- fused leaves (table) + L9 (dual) + L8: one L8 node per thread ----
    {
        const int idx = tid;
        const int p8  = 255 + idx;
        const int p9a = 2 * p8 + 1, p9b = p9a + 1;
        const int xl0 = xs[2 * p9a + 1], xr0 = xs[2 * p9a + 2];
        const int xl1 = xs[2 * p9b + 1], xr1 = xs[2 * p9b + 2];
        const int xva = xs[p9a], xvb = xs[p9b], xv8 = xs[p8];

        const float* pl0 = &sPB[xl0 * BTS];
        const float* pr0 = &sPB[xr0 * BTS];
        const float* pl1 = &sPB[xl1 * BTS];
        const float* pr1 = &sPB[xr1 * BTS];
        float4 sa[4], sb[4];
        #pragma unroll
        for (int q = 0; q < 4; ++q) {
            sa[q] = f4add(*(const float4*)(pl0 + 4*q), *(const float4*)(pr0 + 4*q));
            sb[q] = f4add(*(const float4*)(pl1 + 4*q), *(const float4*)(pr1 + 4*q));
        }
        ll += sLog[xl0] + sLog[xr0] + sLog[xl1] + sLog[xr1];

        float4 bpa[4], bpb[4]; float nua, nub;
        colmv2(sAt, &sBt[xva * BTS], &sBt[xvb * BTS], sa, sb, bpa, bpb, nua, nub);
        ll += __logf(nua) + __logf(nub);
        const float ia = 0.5f / nua, ib = 0.5f / nub;
        float4 s8v[4];
        #pragma unroll
        for (int q = 0; q < 4; ++q)
            s8v[q] = f4add(f4mul(bpa[q], make_float4(ia, ia, ia, ia)),
                           f4mul(bpb[q], make_float4(ib, ib, ib, ib)));
        __builtin_amdgcn_sched_barrier(0);   // liveness fence: subtrees done

        float4 bp[4];
        const float nu = colmv(sAt, &sBt[xv8 * BTS], s8v, bp);
        ll += __logf(nu);
        const float inv = 1.f / nu;
        #pragma unroll
        for (int q = 0; q < 4; ++q) {
            buf0[(4*q + 0) * 256 + idx] = bp[q].x * inv;
            buf0[(4*q + 1) * 256 + idx] = bp[q].y * inv;
            buf0[(4*q + 2) * 256 + idx] = bp[q].z * inv;
            buf0[(4*q + 3) * 256 + idx] = bp[q].w * inv;
        }
    }
    __syncthreads();

    // ---- L7: 128 nodes, batched 2/thread (shared A-column loads) ----
    if (tid < 64) {
        const int t2 = tid;
        float4 sa[4], sb[4];
        #pragma unroll
        for (int q = 0; q < 4; ++q) {
            // children of node pair (2t2, 2t2+1) = 4 contiguous floats: one b128
            float4 v0 = *(const float4*)(&buf0[(4*q + 0) * 256 + 4 * t2]);
            float4 v1 = *(const float4*)(&buf0[(4*q + 1) * 256 + 4 * t2]);
            float4 v2 = *(const float4*)(&buf0[(4*q + 2) * 256 + 4 * t2]);
            float4 v3 = *(const float4*)(&buf0[(4*q + 3) * 256 + 4 * t2]);
            sa[q] = make_float4(0.5f*(v0.x+v0.y), 0.5f*(v1.x+v1.y),
                                0.5f*(v2.x+v2.y), 0.5f*(v3.x+v3.y));
            sb[q] = make_float4(0.5f*(v0.z+v0.w), 0.5f*(v1.z+v1.w),
                                0.5f*(v2.z+v2.w), 0.5f*(v3.z+v3.w));
        }
        const int n0 = 2 * t2, n1 = n0 + 1;
        const int xa = xs[127 + n0], xb = xs[127 + n1];
        float4 bpa[4], bpb[4]; float nua, nub;
        colmv2(sAt, &sBt[xa * BTS], &sBt[xb * BTS], sa, sb, bpa, bpb, nua, nub);
        ll += __logf(nua) + __logf(nub);
        const float ia = 1.f / nua, ib = 1.f / nub;
        #pragma unroll
        for (int q = 0; q < 4; ++q) {
            *(float2*)&buf1[(4*q + 0) * 128 + n0] = make_float2(bpa[q].x*ia, bpb[q].x*ib);
            *(float2*)&buf1[(4*q + 1) * 128 + n0] = make_float2(bpa[q].y*ia, bpb[q].y*ib);
            *(float2*)&buf1[(4*q + 2) * 128 + n0] = make_float2(bpa[q].z*ia, bpb[q].z*ib);
            *(float2*)&buf1[(4*q + 3) * 128 + n0] = make_float2(bpa[q].w*ia, bpb[q].w*ib);
        }
    }
    __syncthreads();

    // ---- L6..L1 (64..2 nodes, batched 2/thread) + root: wave 0 only ----
    if (tid < 64) {
        float* cur = buf1; int cs = 128;
        float* nxt = buf0; int ns = 256;
        for (int cnt2 = 64; cnt2 >= 2; cnt2 >>= 1) {
            if (tid < (cnt2 >> 1)) {
                const int t2 = tid;
                float4 sa[4], sb[4];
                #pragma unroll
                for (int q = 0; q < 4; ++q) {
                    float4 v0 = *(const float4*)(&cur[(4*q + 0) * cs + 4 * t2]);
                    float4 v1 = *(const float4*)(&cur[(4*q + 1) * cs + 4 * t2]);
                    float4 v2 = *(const float4*)(&cur[(4*q + 2) * cs + 4 * t2]);
                    float4 v3 = *(const float4*)(&cur[(4*q + 3) * cs + 4 * t2]);
                    sa[q] = make_float4(0.5f*(v0.x+v0.y), 0.5f*(v1.x+v1.y),
                                        0.5f*(v2.x+v2.y), 0.5f*(v3.x+v3.y));
                    sb[q] = make_float4(0.5f*(v0.z+v0.w), 0.5f*(v1.z+v1.w),
                                        0.5f*(v2.z+v2.w), 0.5f*(v3.z+v3.w));
                }
                const int n0 = 2 * t2, n1 = n0 + 1;
                const int xa = xs[cnt2 - 1 + n0], xb = xs[cnt2 - 1 + n1];
                float4 bpa[4], bpb[4]; float nua, nub;
                colmv2(sAt, &sBt[xa * BTS], &sBt[xb * BTS], sa, sb, bpa, bpb, nua, nub);
                ll += __logf(nua) + __logf(nub);
                const float ia = 1.f / nua, ib = 1.f / nub;
                #pragma unroll
                for (int q = 0; q < 4; ++q) {
                    *(float2*)&nxt[(4*q + 0) * ns + n0] = make_float2(bpa[q].x*ia, bpb[q].x*ib);
                    *(float2*)&nxt[(4*q + 1) * ns + n0] = make_float2(bpa[q].y*ia, bpb[q].y*ib);
                    *(float2*)&nxt[(4*q + 2) * ns + n0] = make_float2(bpa[q].z*ia, bpb[q].z*ib);
                    *(float2*)&nxt[(4*q + 3) * ns + n0] = make_float2(bpa[q].w*ia, bpb[q].w*ib);
                }
            }
            asm volatile("s_waitcnt lgkmcnt(0)" ::: "memory");
            __builtin_amdgcn_wave_barrier();
            float* tp = cur; cur = nxt; nxt = tp;
            int ts = cs; cs = ns; ns = ts;
        }
        // root (1 node): reads the 2-node level from cur
        if (tid == 0) {
            float4 sv[4];
            #pragma unroll
            for (int q = 0; q < 4; ++q) {
                float2 a0 = *(const float2*)(&cur[(4*q + 0) * cs]);
                float2 a1 = *(const float2*)(&cur[(4*q + 1) * cs]);
                float2 a2 = *(const float2*)(&cur[(4*q + 2) * cs]);
                float2 a3 = *(const float2*)(&cur[(4*q + 3) * cs]);
                sv[q] = make_float4(0.5f*(a0.x+a0.y), 0.5f*(a1.x+a1.y),
                                    0.5f*(a2.x+a2.y), 0.5f*(a3.x+a3.y));
            }
            float4 bp[4];
            const float nu = colmv(sAt, &sBt[xs[0] * BTS], sv, bp);
            ll += __logf(nu);   // root beta itself is not needed
        }
    }

    // ---- reduce ll across block ----
    float v = ll;
    #pragma unroll
    for (int off = 32; off > 0; off >>= 1) v += __shfl_down(v, off, 64);
    if ((tid & 63) == 0) wsum[tid >> 6] = v;
    __syncthreads();
    if (tid == 0) out[t * G_DIM + g] = wsum[0] + wsum[1] + wsum[2] + wsum[3];
}

extern "C" void kernel_launch(void* const* d_in, const int* in_sizes, int n_in,
                              void* d_out, int out_size, void* d_ws, size_t ws_size,
                              hipStream_t stream) {
    const int*   x       = (const int*)d_in[0];
    const int*   inv_map = (const int*)d_in[6];
    const float* lA      = (const float*)d_in[7];
    const float* lB      = (const float*)d_in[8];
    const float* lPi     = (const float*)d_in[9];
    float* out = (float*)d_out;

    htmm_fused<<<dim3(NBLOCKS), dim3(256), 0, stream>>>(
        x, inv_map, lA, lB, lPi, out);
}

// Round 10
// 112.538 us; speedup vs baseline: 1.6027x; 1.6027x over previous
//
#include <hip/hip_runtime.h>

// UniformBottomUpHTMM: T=64 trees, depth 10 (N1=2047 heap), C=16, M=64,
// G=16. r21: r19 revert + occupancy push to 5 blocks/CU.
// r20 post-mortem: dual-matvec batching ballooned VGPR to 208 (8 f4
// accumulators + dual inputs co-live) -> 2 waves/SIMD -> 115us. Reverted.
// r19 (row-major fenced matvec, VGPR=108, 56us) is the champion; 73% of
// its cycles are latency stall and occupancy is the proven lever
// (r17 8 waves/CU = 82us -> r19 16 waves/CU = 56us).
// r19's residency limiter is LDS (38400B -> 4 blocks/CU). Diet:
//  - sPB/sLog/sPi (5.4KB, dead after leaf phase) UNION with buf1 (8KB,
//    first written in L7, after the leaf __syncthreads). Saves 5.4KB.
//  - wsum (16B) -> buf0 row15 cols252-255 (tail phase only touches
//    cols<64; L7's full-width reads complete before any wsum write --
//    race-checked including wave0-in-tail vs waves1-3-at-reduce overlap).
//  => total EXACTLY 32768B -> 5 blocks/CU (163840B = 160KB exactly).
//  - amdgpu_waves_per_eu(5): VGPR budget 512/5=102 (r19 demand 108;
//    fenced liveness is bounded, expect ~minor rematerialization).
// Tripwires: WRITE_SIZE >> 4KB => the reg squeeze spilled, revert attr.
//            LDS_Block_Size > 32768 => union miscounted, 4 blocks (neutral).
// Structure: 1024 independent blocks, one (t,g) each, no workspace/atomics.

#define C_DIM 16
#define M_DIM 64
#define G_DIM 16
#define T_TREES 64
#define N1 2047
#define NBLOCKS (T_TREES * G_DIM)   // 1024
#define BTS 20                      // padded row stride (floats) for xv-tables

__device__ __forceinline__ float4 f4add(float4 a, float4 b) {
    return make_float4(a.x + b.x, a.y + b.y, a.z + b.z, a.w + b.w);
}
__device__ __forceinline__ float4 f4mul(float4 a, float4 b) {
    return make_float4(a.x * b.x, a.y * b.y, a.z * b.z, a.w * b.w);
}
__device__ __forceinline__ float4 f4fma(float4 a, float4 b, float4 c) {
    return make_float4(fmaf(a.x, b.x, c.x), fmaf(a.y, b.y, c.y),
                       fmaf(a.z, b.z, c.z), fmaf(a.w, b.w, c.w));
}
__device__ __forceinline__ float hsum4(float4 a) { return a.x + a.y + a.z + a.w; }

// bp[q] = (A[4q+r]·s) * Bt[4q+r]; returns nu = sum(bp).
// Two 8-row halves with a hard sched fence between (r19-proven: caps
// in-flight ds_read_b128 liveness; VGPR 108).
__device__ __forceinline__ float matvec_bt(const float* __restrict__ A,
                                           const float* __restrict__ bt,
                                           const float4 sv[4], float4 bp[4])
{
    float nu = 0.f;
    #pragma unroll
    for (int h = 0; h < 2; ++h) {
        #pragma unroll
        for (int q = 2 * h; q < 2 * h + 2; ++q) {
            const float4 b4 = *(const float4*)(bt + 4 * q);
            float tr[4];
            #pragma unroll
            for (int r = 0; r < 4; ++r) {
                const float4* ar = (const float4*)(A + (4 * q + r) * 16);
                float4 m = f4mul(ar[0], sv[0]);
                m = f4fma(ar[1], sv[1], m);
                m = f4fma(ar[2], sv[2], m);
                m = f4fma(ar[3], sv[3], m);
                tr[r] = hsum4(m);
            }
            bp[q] = f4mul(make_float4(tr[0], tr[1], tr[2], tr[3]), b4);
            nu += hsum4(bp[q]);
        }
        __builtin_amdgcn_sched_barrier(0);   // liveness fence: half-matvec
    }
    return nu;
}

__global__ __attribute__((amdgpu_flat_work_group_size(256, 256),
                          amdgpu_waves_per_eu(5)))
void htmm_fused(
    const int* __restrict__ x,
    const int* __restrict__ inv_map,
    const float* __restrict__ lA,
    const float* __restrict__ lB,
    const float* __restrict__ lPi,
    float* __restrict__ out)
{
    const int bid = blockIdx.x;           // 1024 blocks: g = bid>>6, t = bid&63
    const int tid = threadIdx.x;
    const int g = bid >> 6;
    const int t = bid & (T_TREES - 1);

    // ---- manual LDS layout: EXACTLY 32768 B -> 5 blocks/CU ----
    __shared__ __align__(16) unsigned char smem[32768];
    float* const sA   = (float*)(smem);            //     0 .. 1024   A row-major
    float* const sBt  = (float*)(smem + 1024);     //  1024 .. 6144   Bt[xv][c] stride 20
    float* const sPB  = (float*)(smem + 6144);     //  6144 .. 11264  leaf tables (dead after leaf)
    float* const sLog = (float*)(smem + 11264);    // 11264 .. 11520  (dead after leaf)
    float* const sPi  = (float*)(smem + 11520);    // 11520 .. 11584  (dead after tables)
    float* const buf1 = (float*)(smem + 6144);     // UNION: live from L7 on (8192B)
    unsigned char* const xs = smem + 14336;        // 14336 .. 16384
    float* const buf0 = (float*)(smem + 16384);    // 16384 .. 32768
    float* const wsum = (float*)(smem + 32752);    // buf0 row15 col252-255 (tail-unused)

    // ---- tree symbols (coalesced; 16 same-tree blocks share L2) ----
    {
        const int base = t * N1;
        for (int i = tid; i < N1; i += 256)
            xs[i] = (unsigned char)x[inv_map[base + i]];
    }
    // ---- A softmax (over i within 16-lane segments) ----
    {
        int j = tid >> 4, i = tid & 15;
        float v = lA[(i * C_DIM + j) * G_DIM + g];
        float mx = v;
        #pragma unroll
        for (int m = 1; m < 16; m <<= 1) mx = fmaxf(mx, __shfl_xor(mx, m, 16));
        float e = __expf(v - mx);
        float s = e;
        #pragma unroll
        for (int m = 1; m < 16; m <<= 1) s += __shfl_xor(s, m, 16);
        sA[i * C_DIM + j] = e / s;
    }
    // ---- B softmax (over m), written TRANSPOSED: sBt[xv*BTS + c] ----
    {
        int c = tid >> 4, l16 = tid & 15;
        float e0 = lB[(c * M_DIM + l16 +  0) * G_DIM + g];
        float e1 = lB[(c * M_DIM + l16 + 16) * G_DIM + g];
        float e2 = lB[(c * M_DIM + l16 + 32) * G_DIM + g];
        float e3 = lB[(c * M_DIM + l16 + 48) * G_DIM + g];
        float mx = fmaxf(fmaxf(e0, e1), fmaxf(e2, e3));
        #pragma unroll
        for (int m = 1; m < 16; m <<= 1) mx = fmaxf(mx, __shfl_xor(mx, m, 16));
        e0 = __expf(e0 - mx); e1 = __expf(e1 - mx);
        e2 = __expf(e2 - mx); e3 = __expf(e3 - mx);
        float s = e0 + e1 + e2 + e3;
        #pragma unroll
        for (int m = 1; m < 16; m <<= 1) s += __shfl_xor(s, m, 16);
        float inv = 1.f / s;
        sBt[(l16 +  0) * BTS + c] = e0 * inv;
        sBt[(l16 + 16) * BTS + c] = e1 * inv;
        sBt[(l16 + 32) * BTS + c] = e2 * inv;
        sBt[(l16 + 48) * BTS + c] = e3 * inv;
    }
    if (tid < C_DIM) {  // Pi softmax
        float v = lPi[tid * G_DIM + g];
        float mx = v;
        #pragma unroll
        for (int m = 1; m < 16; m <<= 1) mx = fmaxf(mx, __shfl_xor(mx, m, 16));
        float e = __expf(v - mx);
        float s = e;
        #pragma unroll
        for (int m = 1; m < 16; m <<= 1) s += __shfl_xor(s, m, 16);
        sPi[tid] = e / s;
    }
    __syncthreads();

    // ---- leaf tables: PB[xv][k] = 0.5*Pi[k]*Bt[xv][k]/nu, logNu[xv] ----
    if (tid < M_DIM) {
        const int xv = tid;
        float pb[16]; float nu = 0.f;
        #pragma unroll
        for (int k = 0; k < 16; ++k) {
            pb[k] = sPi[k] * sBt[xv * BTS + k];
            nu += pb[k];
        }
        const float inv = 0.5f / nu;
        #pragma unroll
        for (int k = 0; k < 16; ++k) sPB[xv * BTS + k] = pb[k] * inv;
        sLog[xv] = __logf(nu);
    }
    __syncthreads();

    float ll = 0.f;

    // ---- fused leaves (table) + L9 + L8: one L8 node per thread ----
    {
        const int idx = tid;
        const int p8  = 255 + idx;
        float4 s8v[4];
        #pragma unroll
        for (int q = 0; q < 4; ++q) s8v[q] = make_float4(0.f, 0.f, 0.f, 0.f);

        #pragma unroll
        for (int c9 = 0; c9 < 2; ++c9) {
            const int p9 = 2 * p8 + 1 + c9;
            const int xl = xs[2 * p9 + 1], xr = xs[2 * p9 + 2];
            const float* pl = &sPB[xl * BTS];
            const float* pr = &sPB[xr * BTS];
            float4 s9v[4];
            #pragma unroll
            for (int q = 0; q < 4; ++q)
                s9v[q] = f4add(*(const float4*)(pl + 4*q), *(const float4*)(pr + 4*q));
            ll += sLog[xl] + sLog[xr];

            const int xv = xs[p9];
            float4 bp[4];
            float nu = matvec_bt(sA, &sBt[xv * BTS], s9v, bp);
            ll += __logf(nu);
            const float inv = 0.5f / nu;
            const float4 iv = make_float4(inv, inv, inv, inv);
            #pragma unroll
            for (int q = 0; q < 4; ++q) s8v[q] = f4fma(bp[q], iv, s8v[q]);
            __builtin_amdgcn_sched_barrier(0);   // liveness fence: subtree done
        }
        const int xv = xs[p8];
        float4 bp[4];
        float nu = matvec_bt(sA, &sBt[xv * BTS], s8v, bp);
        ll += __logf(nu);
        const float inv = 1.f / nu;
        #pragma unroll
        for (int q = 0; q < 4; ++q) {
            buf0[(4*q + 0) * 256 + idx] = bp[q].x * inv;
            buf0[(4*q + 1) * 256 + idx] = bp[q].y * inv;
            buf0[(4*q + 2) * 256 + idx] = bp[q].z * inv;
            buf0[(4*q + 3) * 256 + idx] = bp[q].w * inv;
        }
    }
    __syncthreads();

    // ---- L7: 128 nodes (buf1 now aliases the dead sPB region) ----
    if (tid < 128) {
        const int idx = tid;
        float4 sv[4];
        #pragma unroll
        for (int q = 0; q < 4; ++q) {
            float2 c0 = *(const float2*)(&buf0[(4*q + 0) * 256 + 2 * idx]);
            float2 c1 = *(const float2*)(&buf0[(4*q + 1) * 256 + 2 * idx]);
            float2 c2 = *(const float2*)(&buf0[(4*q + 2) * 256 + 2 * idx]);
            float2 c3 = *(const float2*)(&buf0[(4*q + 3) * 256 + 2 * idx]);
            sv[q] = make_float4(0.5f * (c0.x + c0.y), 0.5f * (c1.x + c1.y),
                                0.5f * (c2.x + c2.y), 0.5f * (c3.x + c3.y));
        }
        const int xv = xs[127 + idx];
        float4 bp[4];
        float nu = matvec_bt(sA, &sBt[xv * BTS], sv, bp);
        ll += __logf(nu);
        const float inv = 1.f / nu;
        #pragma unroll
        for (int q = 0; q < 4; ++q) {
            buf1[(4*q + 0) * 128 + idx] = bp[q].x * inv;
            buf1[(4*q + 1) * 128 + idx] = bp[q].y * inv;
            buf1[(4*q + 2) * 128 + idx] = bp[q].z * inv;
            buf1[(4*q + 3) * 128 + idx] = bp[q].w * inv;
        }
    }
    __syncthreads();

    // ---- L6..L0 (64..1 nodes): wave 0 only, LDS fences not barriers ----
    if (tid < 64) {
        float* cur = buf1; int cs = 128;
        float* nxt = buf0; int ns = 256;
        for (int cnt2 = 64; cnt2 >= 1; cnt2 >>= 1) {
            if (tid < cnt2) {
                const int idx = tid;
                float4 sv[4];
                #pragma unroll
                for (int q = 0; q < 4; ++q) {
                    float2 c0 = *(const float2*)(&cur[(4*q + 0) * cs + 2 * idx]);
                    float2 c1 = *(const float2*)(&cur[(4*q + 1) * cs + 2 * idx]);
                    float2 c2 = *(const float2*)(&cur[(4*q + 2) * cs + 2 * idx]);
                    float2 c3 = *(const float2*)(&cur[(4*q + 3) * cs + 2 * idx]);
                    sv[q] = make_float4(0.5f * (c0.x + c0.y), 0.5f * (c1.x + c1.y),
                                        0.5f * (c2.x + c2.y), 0.5f * (c3.x + c3.y));
                }
                const int xv = xs[cnt2 - 1 + idx];
                float4 bp[4];
                float nu = matvec_bt(sA, &sBt[xv * BTS], sv, bp);
                ll += __logf(nu);
                const float inv = 1.f / nu;
                #pragma unroll
                for (int q = 0; q < 4; ++q) {
                    nxt[(4*q + 0) * ns + idx] = bp[q].x * inv;
                    nxt[(4*q + 1) * ns + idx] = bp[q].y * inv;
                    nxt[(4*q + 2) * ns + idx] = bp[q].z * inv;
                    nxt[(4*q + 3) * ns + idx] = bp[q].w * inv;
                }
            }
            asm volatile("s_waitcnt lgkmcnt(0)" ::: "memory");
            __builtin_amdgcn_wave_barrier();
            float* tp = cur; cur = nxt; nxt = tp;
            int ts = cs; cs = ns; ns = ts;
        }
    }

    // ---- reduce ll across block (wsum lives in buf0's tail-unused corner) ----
    float v = ll;
    #pragma unroll
    for (int off = 32; off > 0; off >>= 1) v += __shfl_down(v, off, 64);
    if ((tid & 63) == 0) wsum[tid >> 6] = v;
    __syncthreads();
    if (tid == 0) out[t * G_DIM + g] = wsum[0] + wsum[1] + wsum[2] + wsum[3];
}

extern "C" void kernel_launch(void* const* d_in, const int* in_sizes, int n_in,
                              void* d_out, int out_size, void* d_ws, size_t ws_size,
                              hipStream_t stream) {
    const int*   x       = (const int*)d_in[0];
    const int*   inv_map = (const int*)d_in[6];
    const float* lA      = (const float*)d_in[7];
    const float* lB      = (const float*)d_in[8];
    const float* lPi     = (const float*)d_in[9];
    float* out = (float*)d_out;

    htmm_fused<<<dim3(NBLOCKS), dim3(256), 0, stream>>>(
        x, inv_map, lA, lB, lPi, out);
}